// Round 6
// baseline (6494.183 us; speedup 1.0000x reference)
//
#include <hip/hip_runtime.h>
#include <math.h>

#define BB 64
#define TT 512
#define DD 128
#define HH 512
#define NWG 128

// 8 agent-coherent 8B loads (h,gen pairs), column stride 512B, one clause.
#define LOADC8(d0,d1,d2,d3,d4,d5,d6,d7, ptr)                                  \
  asm volatile("global_load_dwordx2 %0, %8, off sc0 sc1\n\t"                  \
               "global_load_dwordx2 %1, %8, off offset:512 sc0 sc1\n\t"       \
               "global_load_dwordx2 %2, %8, off offset:1024 sc0 sc1\n\t"      \
               "global_load_dwordx2 %3, %8, off offset:1536 sc0 sc1\n\t"      \
               "global_load_dwordx2 %4, %8, off offset:2048 sc0 sc1\n\t"      \
               "global_load_dwordx2 %5, %8, off offset:2560 sc0 sc1\n\t"      \
               "global_load_dwordx2 %6, %8, off offset:3072 sc0 sc1\n\t"      \
               "global_load_dwordx2 %7, %8, off offset:3584 sc0 sc1"          \
               : "=v"(d0), "=v"(d1), "=v"(d2), "=v"(d3),                      \
                 "=v"(d4), "=v"(d5), "=v"(d6), "=v"(d7)                       \
               : "v"(ptr) : "memory")

// ---------------------------------------------------------------------------
// Pre-kernel: transpose U into utT[quad][k][16], r = jp*4 + g.
// ---------------------------------------------------------------------------
__global__ __launch_bounds__(256) void uT_kernel(
    const float* __restrict__ Ui_w, const float* __restrict__ Uf_w,
    const float* __restrict__ Uo_w, const float* __restrict__ Ug_w,
    float* __restrict__ utT)
{
    const int q = blockIdx.x;
    const int jj0 = q << 2;
    for (int k = threadIdx.x; k < HH; k += 256) {
        float v[16];
        #pragma unroll
        for (int r = 0; r < 16; ++r) {
            const int jp = r >> 2, g = r & 3;
            const float* U = (g == 0) ? Ui_w : (g == 1) ? Uf_w : (g == 2) ? Uo_w : Ug_w;
            v[r] = U[(size_t)(jj0 + jp) * HH + k];
        }
        float4* dst = (float4*)(utT + ((size_t)q * HH + k) * 16);
        dst[0] = make_float4(v[0], v[1], v[2], v[3]);
        dst[1] = make_float4(v[4], v[5], v[6], v[7]);
        dst[2] = make_float4(v[8], v[9], v[10], v[11]);
        dst[3] = make_float4(v[12], v[13], v[14], v[15]);
    }
}

// ---------------------------------------------------------------------------
// Phase A: x-projections. out[bt*HH + jj], bt = b*T + t.
// ---------------------------------------------------------------------------
__global__ __launch_bounds__(512) void xproj_kernel(
    const float* __restrict__ x,
    const float* __restrict__ Wi_w, const float* __restrict__ Wi_b,
    const float* __restrict__ Wf_w, const float* __restrict__ Wf_b,
    const float* __restrict__ Wo_w, const float* __restrict__ Wo_b,
    const float* __restrict__ Wg_w, const float* __restrict__ Wg_b,
    float* __restrict__ xi, float* __restrict__ xf,
    float* __restrict__ xo, float* __restrict__ xg)
{
    const int tid  = threadIdx.x;
    const int w    = tid >> 6;
    const int lane = tid & 63;
    const int g     = w >> 1;
    const int jhalf = w & 1;
    const int bt0   = blockIdx.x * 128;

    const float* W  = (g == 0) ? Wi_w : (g == 1) ? Wf_w : (g == 2) ? Wo_w : Wg_w;
    const float* Bv = (g == 0) ? Wi_b : (g == 1) ? Wf_b : (g == 2) ? Wo_b : Wg_b;
    float* out      = (g == 0) ? xi   : (g == 1) ? xf   : (g == 2) ? xo   : xg;

    for (int blk = 0; blk < 4; ++blk) {
        const int jj = jhalf * 256 + blk * 64 + lane;
        float4 wr[32];
        const float4* wsrc = (const float4*)(W + (size_t)jj * DD);
        #pragma unroll
        for (int i = 0; i < 32; ++i) wr[i] = wsrc[i];
        const float bias = Bv[jj];

        for (int bt = bt0; bt < bt0 + 128; ++bt) {
            const float4* xr = (const float4*)(x + (size_t)bt * DD);
            float acc = bias;
            #pragma unroll
            for (int i = 0; i < 32; ++i) {
                const float4 xv = xr[i];
                acc += xv.x * wr[i].x + xv.y * wr[i].y + xv.z * wr[i].z + xv.w * wr[i].w;
            }
            out[(size_t)bt * HH + jj] = acc;
        }
    }
}

// ---------------------------------------------------------------------------
// Persistent recurrence, tagged (h,gen) 8B exchange — no flags, no release
// drain. 128 WGs x 512 thr. WG owns quad = ((wg&7)<<4)|(wg>>3), jj0 = quad*4.
// Wave w covers k in [w*64, w*64+64). htag[2][HH][BB] of uint64.
// ---------------------------------------------------------------------------
__global__ __launch_bounds__(512, 2) void lstm_persist(
    const float* __restrict__ utT,
    const float* __restrict__ Ui_w, const float* __restrict__ Uf_w,
    const float* __restrict__ Ug_w,
    float* __restrict__ b_i, float* __restrict__ b_f,   // xi->hs, xf->fs
    float* __restrict__ b_o, float* __restrict__ b_g,   // xo->es, xg->cds
    unsigned long long* __restrict__ htag)              // [2][HH][BB]
{
    __shared__ float red[2][8][16][64];   // 64 KB, parity-double-buffered
    __shared__ float sh[2][4][64][4];     // 8 KB  [parity][arr][b][jp]

    const int tid  = threadIdx.x;
    const int w    = tid >> 6;
    const int lane = tid & 63;
    const int wg   = blockIdx.x;
    const int quad = ((wg & 7) << 4) | (wg >> 3);
    const int jj0  = quad << 2;
    const int k0   = w << 6;

    const unsigned uoff = (unsigned)__builtin_amdgcn_readfirstlane(k0 << 4);
    const float4* up4 = (const float4*)(utT + (size_t)quad * (HH * 16) + uoff);

    float creg = 0.f, uid = 0.f, ufd = 0.f, ugd = 0.f;
    const int jp = (w < 4) ? w : 0;
    const int jj = jj0 + jp;
    if (w < 4) {
        uid = Ui_w[(size_t)jj * HH + jj];
        ufd = Uf_w[(size_t)jj * HH + jj];
        ugd = Ug_w[(size_t)jj * HH + jj];
    }

    for (int t = 0; t < TT; ++t) {
        const int p  = t & 1;
        const int np = p ^ 1;

        // xp prefetch: plain cached loads, in flight through the poll
        float xpi = 0.f, xpf = 0.f, xpo = 0.f, xpg = 0.f;
        size_t adr = 0;
        if (w < 4) {
            adr = (size_t)lane * TT * HH + (size_t)t * HH + jj;
            xpi = b_i[adr]; xpf = b_f[adr]; xpo = b_o[adr]; xpg = b_g[adr];
        }

        // ---- cheap diagonal pre-poll: lane probes (col k0+lane, batch lane) ----
        {
            const int* tagp = (const int*)&htag[((size_t)p * HH + k0 + lane) * BB + lane] + 1;
            while (true) {
                const int g = __hip_atomic_load(tagp, __ATOMIC_RELAXED,
                                                __HIP_MEMORY_SCOPE_AGENT);
                if (__all(g >= t)) break;
                __builtin_amdgcn_s_sleep(2);
            }
        }

        // ---- full tagged clause + verify (retry rare) ----
        unsigned long long hv[64];
        const char* hp = (const char*)(htag + ((size_t)p * HH + k0) * BB) + lane * 8;
        for (;;) {
            LOADC8(hv[0], hv[1], hv[2], hv[3], hv[4], hv[5], hv[6], hv[7],  hp);
            LOADC8(hv[8], hv[9], hv[10],hv[11],hv[12],hv[13],hv[14],hv[15], hp + 4096);
            LOADC8(hv[16],hv[17],hv[18],hv[19],hv[20],hv[21],hv[22],hv[23], hp + 8192);
            LOADC8(hv[24],hv[25],hv[26],hv[27],hv[28],hv[29],hv[30],hv[31], hp + 12288);
            LOADC8(hv[32],hv[33],hv[34],hv[35],hv[36],hv[37],hv[38],hv[39], hp + 16384);
            LOADC8(hv[40],hv[41],hv[42],hv[43],hv[44],hv[45],hv[46],hv[47], hp + 20480);
            LOADC8(hv[48],hv[49],hv[50],hv[51],hv[52],hv[53],hv[54],hv[55], hp + 24576);
            LOADC8(hv[56],hv[57],hv[58],hv[59],hv[60],hv[61],hv[62],hv[63], hp + 28672);
            asm volatile("s_waitcnt vmcnt(0)" ::: "memory");
            __builtin_amdgcn_sched_barrier(0);

            int mg = 0x7fffffff;
            #pragma unroll
            for (int i = 0; i < 64; ++i) mg = min(mg, (int)(unsigned)(hv[i] >> 32));
            if (__all(mg >= t)) break;
            __builtin_amdgcn_s_sleep(1);
        }

        float acc[16];
        #pragma unroll
        for (int r = 0; r < 16; ++r) acc[r] = 0.f;

        #pragma unroll
        for (int i = 0; i < 64; ++i) {
            const float4 u0 = up4[(i << 2) + 0];
            const float4 u1 = up4[(i << 2) + 1];
            const float4 u2 = up4[(i << 2) + 2];
            const float4 u3 = up4[(i << 2) + 3];
            const float hvf = __uint_as_float((unsigned)hv[i]);
            acc[0]  = fmaf(u0.x, hvf, acc[0]);
            acc[1]  = fmaf(u0.y, hvf, acc[1]);
            acc[2]  = fmaf(u0.z, hvf, acc[2]);
            acc[3]  = fmaf(u0.w, hvf, acc[3]);
            acc[4]  = fmaf(u1.x, hvf, acc[4]);
            acc[5]  = fmaf(u1.y, hvf, acc[5]);
            acc[6]  = fmaf(u1.z, hvf, acc[6]);
            acc[7]  = fmaf(u1.w, hvf, acc[7]);
            acc[8]  = fmaf(u2.x, hvf, acc[8]);
            acc[9]  = fmaf(u2.y, hvf, acc[9]);
            acc[10] = fmaf(u2.z, hvf, acc[10]);
            acc[11] = fmaf(u2.w, hvf, acc[11]);
            acc[12] = fmaf(u3.x, hvf, acc[12]);
            acc[13] = fmaf(u3.y, hvf, acc[13]);
            acc[14] = fmaf(u3.z, hvf, acc[14]);
            acc[15] = fmaf(u3.w, hvf, acc[15]);
        }
        #pragma unroll
        for (int r = 0; r < 16; ++r) red[p][w][r][lane] = acc[r];
        __syncthreads();

        if (w < 4) {
            float pre[4];
            #pragma unroll
            for (int g = 0; g < 4; ++g) {
                float s = 0.f;
                #pragma unroll
                for (int wk = 0; wk < 8; ++wk) s += red[p][wk][(jp << 2) + g][lane];
                pre[g] = s;
            }
            const float pi = xpi + pre[0];
            const float pf = xpf + pre[1];
            const float po = xpo + pre[2];
            const float pg = xpg + pre[3];

            const float ig = __fdividef(1.f, 1.f + __expf(-pi));
            const float fg = __fdividef(1.f, 1.f + __expf(-pf));
            const float og = __fdividef(1.f, 1.f + __expf(-po));
            const float tg = __expf(-2.f * fmaxf(pg, -40.f));
            const float gg = __fdividef(1.f - tg, 1.f + tg);

            const float cp = creg;
            const float c  = fg * cp + ig * gg;
            creg = c;
            const float tc = __expf(-2.f * fmaxf(c, -40.f));
            const float th = __fdividef(1.f - tc, 1.f + tc);
            const float h  = og * th;
            const float e  = og * (1.f - th * th);
            const float cd = cp * (fg * (1.f - fg)) * ufd
                           + ig * (1.f - gg * gg) * ugd
                           + gg * (ig * (1.f - ig)) * uid;

            // publish (h, gen t+1) as one 8B store — no drain, no flag
            {
                const unsigned long long pk =
                    ((unsigned long long)(unsigned)(t + 1) << 32) |
                    (unsigned long long)__float_as_uint(h);
                unsigned long long* dp = htag + ((size_t)np * HH + jj) * BB + lane;
                asm volatile("global_store_dwordx2 %0, %1, off sc0 sc1"
                             :: "v"(dp), "v"(pk) : "memory");
            }

            // stage outputs for deferred drain by waves 4-7
            sh[p][0][lane][w] = h;
            sh[p][1][lane][w] = fg;
            sh[p][2][lane][w] = e;
            sh[p][3][lane][w] = cd;
        } else if (t > 0) {
            // drain gen t-1 outputs (ordered by this iter's __syncthreads)
            const int arr = (tid - 256) >> 6;
            float* base = (arr == 0) ? b_i : (arr == 1) ? b_f : (arr == 2) ? b_o : b_g;
            const float4 v = *(const float4*)&sh[np][arr][lane][0];
            *(float4*)(base + (size_t)lane * TT * HH + (size_t)(t - 1) * HH + jj0) = v;
        }
    }

    // drain final step's outputs (gen TT-1 lives in sh[1])
    __syncthreads();
    if (w >= 4) {
        const int arr = (tid - 256) >> 6;
        float* base = (arr == 0) ? b_i : (arr == 1) ? b_f : (arr == 2) ? b_o : b_g;
        const float4 v = *(const float4*)&sh[1][arr][lane][0];
        *(float4*)(base + (size_t)lane * TT * HH + (size_t)(TT - 1) * HH + jj0) = v;
    }
}

// ys[r] = dot(hs[r,:], out_w) + out_b ; one wave per row r = b*T + t
__global__ __launch_bounds__(256) void lstm_y(
    const float* __restrict__ hs, const float* __restrict__ out_w,
    const float* __restrict__ out_b, float* __restrict__ ys)
{
    const int wave = threadIdx.x >> 6;
    const int lane = threadIdx.x & 63;
    const int r = blockIdx.x * 4 + wave;

    const float4* hv = (const float4*)(hs + (size_t)r * HH);
    const float4* wv = (const float4*)out_w;
    float acc = 0.f;
    #pragma unroll
    for (int i = 0; i < 2; ++i) {
        float4 h4 = hv[lane * 2 + i];
        float4 w4 = wv[lane * 2 + i];
        acc += h4.x * w4.x + h4.y * w4.y + h4.z * w4.z + h4.w * w4.w;
    }
    #pragma unroll
    for (int m = 32; m >= 1; m >>= 1) acc += __shfl_xor(acc, m, 64);
    if (lane == 0) ys[r] = acc + out_b[0];
}

extern "C" void kernel_launch(void* const* d_in, const int* in_sizes, int n_in,
                              void* d_out, int out_size, void* d_ws, size_t ws_size,
                              hipStream_t stream)
{
    const float* x    = (const float*)d_in[0];
    const float* Wi_w = (const float*)d_in[1];
    const float* Wi_b = (const float*)d_in[2];
    const float* Ui_w = (const float*)d_in[3];
    const float* Wf_w = (const float*)d_in[4];
    const float* Wf_b = (const float*)d_in[5];
    const float* Uf_w = (const float*)d_in[6];
    const float* Wo_w = (const float*)d_in[7];
    const float* Wo_b = (const float*)d_in[8];
    const float* Uo_w = (const float*)d_in[9];
    const float* Wg_w = (const float*)d_in[10];
    const float* Wg_b = (const float*)d_in[11];
    const float* Ug_w = (const float*)d_in[12];
    const float* out_w = (const float*)d_in[13];
    const float* out_b = (const float*)d_in[14];

    float* ys  = (float*)d_out;                     // [B*T]
    float* hs  = ys + (size_t)BB * TT;              // [B*T*H]
    float* fs  = hs + (size_t)BB * TT * HH;
    float* es  = fs + (size_t)BB * TT * HH;
    float* cds = es + (size_t)BB * TT * HH;

    // ws layout: [htag 512KB][utT 4MB]
    unsigned long long* htag = (unsigned long long*)d_ws;
    float* utT = (float*)(htag + (size_t)2 * HH * BB);

    // zero htag (gen=0, h=0) every call (graph-replay safe)
    hipMemsetAsync(d_ws, 0, (size_t)2 * HH * BB * sizeof(unsigned long long),
                   stream);

    uT_kernel<<<NWG, 256, 0, stream>>>(Ui_w, Uf_w, Uo_w, Ug_w, utT);

    xproj_kernel<<<256, 512, 0, stream>>>(x, Wi_w, Wi_b, Wf_w, Wf_b,
                                          Wo_w, Wo_b, Wg_w, Wg_b,
                                          hs, fs, es, cds);

    lstm_persist<<<NWG, 512, 0, stream>>>(utT, Ui_w, Uf_w, Ug_w,
                                          hs, fs, es, cds, htag);

    lstm_y<<<(BB * TT) / 4, 256, 0, stream>>>(hs, out_w, out_b, ys);
}